// Round 4
// baseline (909.872 us; speedup 1.0000x reference)
//
#include <hip/hip_runtime.h>
#include <math.h>

#define N_ 20000
#define E_ 320000
#define G_ 128
#define IN_ 16
#define H_ 64
#define L_ 4
#define C_ 10
#define AVG_D_LOG 2.8332133440562162f

union F4 { float4 v; float f[4]; };

// ---------------- preprocessing ----------------

__global__ __launch_bounds__(256) void k_zero(int* __restrict__ p, int n) {
  int i = blockIdx.x * 256 + threadIdx.x;
  if (i < n) p[i] = 0;
}

__global__ __launch_bounds__(256) void k_hist(const int* __restrict__ dst, int* __restrict__ deg) {
  int e = blockIdx.x * 256 + threadIdx.x;
  if (e < E_) atomicAdd(&deg[dst[e]], 1);
}

// single-block exclusive scan of deg -> offs, plus degree-derived scalers
__global__ __launch_bounds__(1024) void k_scan(const int* __restrict__ deg, int* __restrict__ offs,
    float* __restrict__ ampv, float* __restrict__ attv,
    float* __restrict__ invd, float* __restrict__ hnb) {
  __shared__ int sh[1024];
  int t = threadIdx.x;
  int base = t * 20;
  int local[20];
  int s = 0;
#pragma unroll
  for (int i = 0; i < 20; i++) {
    int idx = base + i;
    int v = (idx < N_) ? deg[idx] : 0;
    local[i] = s; s += v;
  }
  sh[t] = s;
  __syncthreads();
  for (int off = 1; off < 1024; off <<= 1) {
    int v = (t >= off) ? sh[t - off] : 0;
    __syncthreads();
    sh[t] += v;
    __syncthreads();
  }
  int excl = sh[t] - s;
#pragma unroll
  for (int i = 0; i < 20; i++) {
    int idx = base + i;
    if (idx < N_) offs[idx] = excl + local[i];
  }
  if (t == 0) offs[N_] = sh[1023];
  for (int idx = t; idx < N_; idx += 1024) {
    float d = (float)deg[idx];
    float logd = logf(d + 1.f);
    ampv[idx] = logd / AVG_D_LOG;
    attv[idx] = AVG_D_LOG / fmaxf(logd, 1e-5f);
    invd[idx] = 1.f / fmaxf(d, 1.f);
    hnb[idx] = d > 0.f ? 1.f : 0.f;
  }
}

__global__ __launch_bounds__(256) void k_scatter(const int* __restrict__ src, const int* __restrict__ dst,
    const int* __restrict__ offs, int* __restrict__ cursor, int* __restrict__ csr) {
  int e = blockIdx.x * 256 + threadIdx.x;
  if (e < E_) {
    int d = dst[e];
    int pos = offs[d] + atomicAdd(&cursor[d], 1);
    csr[pos] = src[e];
  }
}

// ---------------- embedding ----------------

__global__ __launch_bounds__(256) void k_embed(const float* __restrict__ h, const float* __restrict__ embW,
    const float* __restrict__ embB, float* __restrict__ x) {
  int n = blockIdx.x * 4 + (threadIdx.x >> 6);
  int c = threadIdx.x & 63;
  float acc = embB[c];
#pragma unroll
  for (int k = 0; k < IN_; k++) acc += h[n * IN_ + k] * embW[k * H_ + c];
  x[n * H_ + c] = acc;
}

// ---------------- pretrans: a = x@W_top, b = x@W_bot + bias ----------------
// 1 wave/block, 16 nodes/wave, grid 1250 (~5 blocks/CU). No LDS: lanes in a
// node-group broadcast-read x rows from global; W streams from L2.

__global__ __launch_bounds__(64, 4) void k_pretrans(const float* __restrict__ x, const float* __restrict__ W,
    const float* __restrict__ Bv, float* __restrict__ a, float* __restrict__ b) {
  int tid = threadIdx.x;
  int n0 = blockIdx.x * 16;
  int cq = tid & 15, ng = tid >> 4;   // ng: node-group 0..3 (4 nodes each)
  int c4 = cq * 4;
  const float* xbase = x + (size_t)(n0 + ng * 4) * 64;
  F4 accA[4], accB[4];
  F4 bias; bias.v = *(const float4*)(Bv + c4);
#pragma unroll
  for (int i = 0; i < 4; i++) {
    accA[i].v = make_float4(0.f, 0.f, 0.f, 0.f);
    accB[i].v = bias.v;
  }
#pragma unroll 2
  for (int k = 0; k < 64; k += 4) {
    F4 av[4];
#pragma unroll
    for (int i = 0; i < 4; i++) av[i].v = *(const float4*)(xbase + i * 64 + k);
#pragma unroll
    for (int kk = 0; kk < 4; kk++) {
      F4 wa, wb;
      wa.v = *(const float4*)(W + (k + kk) * 64 + c4);
      wb.v = *(const float4*)(W + (64 + k + kk) * 64 + c4);
#pragma unroll
      for (int i = 0; i < 4; i++) {
        float m = av[i].f[kk];
#pragma unroll
        for (int j = 0; j < 4; j++) {
          accA[i].f[j] += m * wa.f[j];
          accB[i].f[j] += m * wb.f[j];
        }
      }
    }
  }
#pragma unroll
  for (int i = 0; i < 4; i++) {
    int n = n0 + ng * 4 + i;
    *(float4*)(a + (size_t)n * 64 + c4) = accA[i].v;
    *(float4*)(b + (size_t)n * 64 + c4) = accB[i].v;
  }
}

// ---------------- aggregation: wave per node, 4 edges in flight ----------------

__global__ __launch_bounds__(256) void k_agg(const float* __restrict__ a, const float* __restrict__ b,
    const int* __restrict__ offs, const int* __restrict__ csr,
    const float* __restrict__ invd, const float* __restrict__ hnb, float* __restrict__ agg) {
  int lane = threadIdx.x & 63;
  int n = (blockIdx.x * 256 + threadIdx.x) >> 6;
  int q = lane & 15;    // channel quad: channels 4q..4q+3
  int eg = lane >> 4;   // edge group 0..3
  int o0 = offs[n];
  int deg = offs[n + 1] - o0;
  F4 bv; bv.v = *(const float4*)(b + n * 64 + q * 4);
  F4 sum, sq, mx, mn;
#pragma unroll
  for (int i = 0; i < 4; i++) {
    sum.f[i] = 0.f; sq.f[i] = 0.f;
    mx.f[i] = -__builtin_inff(); mn.f[i] = __builtin_inff();
  }
  for (int j = eg; j < deg; j += 4) {
    int s = csr[o0 + j];
    F4 av; av.v = *(const float4*)(a + s * 64 + q * 4);
#pragma unroll
    for (int i = 0; i < 4; i++) {
      float m = av.f[i] + bv.f[i];
      sum.f[i] += m;
      sq.f[i] += m * m;
      mx.f[i] = fmaxf(mx.f[i], m);
      mn.f[i] = fminf(mn.f[i], m);
    }
  }
#pragma unroll
  for (int off = 16; off < 64; off <<= 1) {
#pragma unroll
    for (int i = 0; i < 4; i++) {
      sum.f[i] += __shfl_xor(sum.f[i], off);
      sq.f[i]  += __shfl_xor(sq.f[i], off);
      mx.f[i]  = fmaxf(mx.f[i], __shfl_xor(mx.f[i], off));
      mn.f[i]  = fminf(mn.f[i], __shfl_xor(mn.f[i], off));
    }
  }
  if (eg == 0) {
    float inv = invd[n], hn = hnb[n];
    F4 mean, stdv, mxo, mno;
#pragma unroll
    for (int i = 0; i < 4; i++) {
      mean.f[i] = sum.f[i] * inv;
      float var = sq.f[i] * inv - mean.f[i] * mean.f[i];
      stdv.f[i] = sqrtf(fmaxf(var, 0.f) + 1e-5f);
      mxo.f[i] = (hn > 0.5f) ? mx.f[i] : 0.f;
      mno.f[i] = (hn > 0.5f) ? mn.f[i] : 0.f;
    }
    *(float4*)(agg + n * 256 + q * 4) = mean.v;
    *(float4*)(agg + n * 256 + 64 + q * 4) = mxo.v;
    *(float4*)(agg + n * 256 + 128 + q * 4) = mno.v;
    *(float4*)(agg + n * 256 + 192 + q * 4) = stdv.v;
  }
}

// ---------------- posttrans + mix + graphnorm + residual (fused) ----------------
// 1 wave/block, 16 nodes, grid 1250. agg read ONCE direct from global
// (broadcast within node-group); 3 accumulator sets; tiny LDS only to
// transpose y between posttrans and mix.

__global__ __launch_bounds__(64, 4) void k_post(
    const float* __restrict__ agg, const float* __restrict__ W, const float* __restrict__ Bv,
    const float* __restrict__ mixW, const float* __restrict__ mixB,
    const float* __restrict__ ampv, const float* __restrict__ attv,
    const float* __restrict__ snorm, float* __restrict__ x) {
  __shared__ float ys[16 * 68];
  int tid = threadIdx.x;
  int n0 = blockIdx.x * 16;
  int cq = tid & 15, ng = tid >> 4;
  int c4 = cq * 4;
  int nb = n0 + ng * 4;                       // first node of this lane's group
  const float* abase = agg + (size_t)nb * 256;
  F4 uI[4], uA[4], uT[4];
#pragma unroll
  for (int i = 0; i < 4; i++) {
    uI[i].v = make_float4(0.f, 0.f, 0.f, 0.f);
    uA[i].v = make_float4(0.f, 0.f, 0.f, 0.f);
    uT[i].v = make_float4(0.f, 0.f, 0.f, 0.f);
  }
  // main GEMM over the 256 agg columns, 3 W segments at once
#pragma unroll 2
  for (int k = 0; k < 256; k += 4) {
    F4 av[4];
#pragma unroll
    for (int i = 0; i < 4; i++) av[i].v = *(const float4*)(abase + i * 256 + k);
#pragma unroll
    for (int kk = 0; kk < 4; kk++) {
      F4 w0, w1, w2;
      w0.v = *(const float4*)(W + (k + kk) * 64 + c4);
      w1.v = *(const float4*)(W + (256 + k + kk) * 64 + c4);
      w2.v = *(const float4*)(W + (512 + k + kk) * 64 + c4);
#pragma unroll
      for (int i = 0; i < 4; i++) {
        float m = av[i].f[kk];
#pragma unroll
        for (int j = 0; j < 4; j++) {
          uI[i].f[j] += m * w0.f[j];
          uA[i].f[j] += m * w1.f[j];
          uT[i].f[j] += m * w2.f[j];
        }
      }
    }
  }
  // x part: rows 768..831 into identity accumulator
  const float* xbase = x + (size_t)nb * 64;
#pragma unroll 2
  for (int k = 0; k < 64; k += 4) {
    F4 xv[4];
#pragma unroll
    for (int i = 0; i < 4; i++) xv[i].v = *(const float4*)(xbase + i * 64 + k);
#pragma unroll
    for (int kk = 0; kk < 4; kk++) {
      F4 w; w.v = *(const float4*)(W + (768 + k + kk) * 64 + c4);
#pragma unroll
      for (int i = 0; i < 4; i++) {
        float m = xv[i].f[kk];
#pragma unroll
        for (int j = 0; j < 4; j++) uI[i].f[j] += m * w.f[j];
      }
    }
  }
  // combine scalers + bias -> stage y into LDS (transpose for mix)
  {
    F4 bias; bias.v = *(const float4*)(Bv + c4);
#pragma unroll
    for (int i = 0; i < 4; i++) {
      float amp = ampv[nb + i], att = attv[nb + i];
      F4 y;
#pragma unroll
      for (int j = 0; j < 4; j++)
        y.f[j] = uI[i].f[j] + bias.f[j] + amp * uA[i].f[j] + att * uT[i].f[j];
      *(float4*)(ys + (ng * 4 + i) * 68 + c4) = y.v;
    }
  }
  __syncthreads();
  // mix: t = leaky_relu(y @ mixW + mixB); x = x_in + t * snorm
  F4 acc[4];
  {
    F4 mb; mb.v = *(const float4*)(mixB + c4);
#pragma unroll
    for (int i = 0; i < 4; i++) acc[i].v = mb.v;
  }
#pragma unroll 2
  for (int k = 0; k < 64; k += 4) {
    F4 yv[4];
#pragma unroll
    for (int i = 0; i < 4; i++) yv[i].v = *(const float4*)(ys + (ng * 4 + i) * 68 + k);
#pragma unroll
    for (int kk = 0; kk < 4; kk++) {
      F4 w; w.v = *(const float4*)(mixW + (k + kk) * 64 + c4);
#pragma unroll
      for (int i = 0; i < 4; i++) {
        float m = yv[i].f[kk];
#pragma unroll
        for (int j = 0; j < 4; j++) acc[i].f[j] += m * w.f[j];
      }
    }
  }
#pragma unroll
  for (int i = 0; i < 4; i++) {
    int n = nb + i;
    float sn = snorm[n];
    F4 xv; xv.v = *(const float4*)(x + (size_t)n * 64 + c4);
    F4 outv;
#pragma unroll
    for (int j = 0; j < 4; j++) {
      float t2 = acc[i].f[j];
      t2 = t2 > 0.f ? t2 : 0.01f * t2;
      outv.f[j] = xv.f[j] + t2 * sn;
    }
    *(float4*)(x + (size_t)n * 64 + c4) = outv.v;
  }
}

// ---------------- fused readout: segmented mean (gid sorted) + MLP ----------------

__device__ inline int lower_bound_gid(const int* __restrict__ gid, int val) {
  int lo = 0, hi = N_;
  while (lo < hi) {
    int mid = (lo + hi) >> 1;
    if (gid[mid] < val) lo = mid + 1; else hi = mid;
  }
  return lo;
}

__global__ __launch_bounds__(256) void k_readout_fused(
    const float* __restrict__ x, const int* __restrict__ gid,
    const float* __restrict__ r1W, const float* __restrict__ r1B,
    const float* __restrict__ r2W, const float* __restrict__ r2B,
    const float* __restrict__ r3W, const float* __restrict__ r3B,
    float* __restrict__ out) {
  __shared__ float part[4 * 64];
  __shared__ float hg[64];
  __shared__ float t1[32];
  __shared__ float t2[16];
  int g = blockIdx.x, tid = threadIdx.x;
  int lo = lower_bound_gid(gid, g);
  int hi = lower_bound_gid(gid, g + 1);
  int c = tid & 63, w = tid >> 6;
  float s = 0.f;
  for (int n = lo + w; n < hi; n += 4) s += x[(size_t)n * 64 + c];
  part[w * 64 + c] = s;
  __syncthreads();
  if (w == 0) {
    float tot = part[c] + part[64 + c] + part[128 + c] + part[192 + c];
    float cnt = (float)(hi - lo);
    if (cnt < 1.f) cnt = 1.f;
    hg[c] = tot / cnt;
  }
  __syncthreads();
  if (tid < 32) {
    float acc = r1B[tid];
#pragma unroll 8
    for (int k = 0; k < 64; k++) acc += hg[k] * r1W[k * 32 + tid];
    t1[tid] = fmaxf(acc, 0.f);
  }
  __syncthreads();
  if (tid < 16) {
    float acc = r2B[tid];
#pragma unroll 8
    for (int k = 0; k < 32; k++) acc += t1[k] * r2W[k * 16 + tid];
    t2[tid] = fmaxf(acc, 0.f);
  }
  __syncthreads();
  if (tid < 10) {
    float acc = r3B[tid];
#pragma unroll
    for (int k = 0; k < 16; k++) acc += t2[k] * r3W[k * 10 + tid];
    out[g * 10 + tid] = acc;
  }
}

// ---------------- launch ----------------

extern "C" void kernel_launch(void* const* d_in, const int* in_sizes, int n_in,
                              void* d_out, int out_size, void* d_ws, size_t ws_size,
                              hipStream_t stream) {
  const float* h     = (const float*)d_in[0];
  const float* snorm = (const float*)d_in[1];
  const float* embW  = (const float*)d_in[2];
  const float* embB  = (const float*)d_in[3];
  const float* preW  = (const float*)d_in[4];
  const float* preB  = (const float*)d_in[5];
  const float* postW = (const float*)d_in[6];
  const float* postB = (const float*)d_in[7];
  const float* mixW  = (const float*)d_in[8];
  const float* mixB  = (const float*)d_in[9];
  const float* r1W   = (const float*)d_in[10];
  const float* r1B   = (const float*)d_in[11];
  const float* r2W   = (const float*)d_in[12];
  const float* r2B   = (const float*)d_in[13];
  const float* r3W   = (const float*)d_in[14];
  const float* r3B   = (const float*)d_in[15];
  const int* src     = (const int*)d_in[16];
  const int* dst     = (const int*)d_in[17];
  const int* gid     = (const int*)d_in[18];
  float* out = (float*)d_out;

  char* w = (char*)d_ws;
  float* x    = (float*)w; w += (size_t)N_ * 64 * 4;
  float* av   = (float*)w; w += (size_t)N_ * 64 * 4;
  float* bv   = (float*)w; w += (size_t)N_ * 64 * 4;
  float* agg  = (float*)w; w += (size_t)N_ * 256 * 4;
  float* ampv = (float*)w; w += (size_t)N_ * 4;
  float* attv = (float*)w; w += (size_t)N_ * 4;
  float* invd = (float*)w; w += (size_t)N_ * 4;
  float* hnb  = (float*)w; w += (size_t)N_ * 4;
  int* csr    = (int*)w;   w += (size_t)E_ * 4;
  int* offs   = (int*)w;   w += (size_t)(N_ + 64) * 4;
  int* zbase  = (int*)w;
  int* deg    = (int*)w;   w += (size_t)N_ * 4;
  int* cursor = (int*)w;   w += (size_t)N_ * 4;
  int zcount = N_ + N_;

  k_zero<<<(zcount + 255) / 256, 256, 0, stream>>>(zbase, zcount);
  k_hist<<<E_ / 256, 256, 0, stream>>>(dst, deg);
  k_scan<<<1, 1024, 0, stream>>>(deg, offs, ampv, attv, invd, hnb);
  k_scatter<<<E_ / 256, 256, 0, stream>>>(src, dst, offs, cursor, csr);
  k_embed<<<N_ / 4, 256, 0, stream>>>(h, embW, embB, x);
  for (int l = 0; l < L_; l++) {
    k_pretrans<<<N_ / 16, 64, 0, stream>>>(x, preW + l * 2 * H_ * H_, preB + l * H_, av, bv);
    k_agg<<<N_ / 4, 256, 0, stream>>>(av, bv, offs, csr, invd, hnb, agg);
    k_post<<<N_ / 16, 64, 0, stream>>>(agg, postW + l * 13 * H_ * H_, postB + l * H_,
                                       mixW + l * H_ * H_, mixB + l * H_, ampv, attv, snorm, x);
  }
  k_readout_fused<<<G_, 256, 0, stream>>>(x, gid, r1W, r1B, r2W, r2B, r3W, r3B, out);
}

// Round 5
// 855.118 us; speedup vs baseline: 1.0640x; 1.0640x over previous
//
#include <hip/hip_runtime.h>
#include <math.h>

#define N_ 20000
#define E_ 320000
#define G_ 128
#define IN_ 16
#define H_ 64
#define L_ 4
#define C_ 10
#define AVG_D_LOG 2.8332133440562162f

union F4 { float4 v; float f[4]; };

// ---------------- preprocessing ----------------

__global__ __launch_bounds__(256) void k_zero(int* __restrict__ p, int n) {
  int i = blockIdx.x * 256 + threadIdx.x;
  if (i < n) p[i] = 0;
}

__global__ __launch_bounds__(256) void k_hist(const int* __restrict__ dst, int* __restrict__ deg) {
  int e = blockIdx.x * 256 + threadIdx.x;
  if (e < E_) atomicAdd(&deg[dst[e]], 1);
}

// single-block exclusive scan of deg -> offs, plus degree-derived scalers
__global__ __launch_bounds__(1024) void k_scan(const int* __restrict__ deg, int* __restrict__ offs,
    float* __restrict__ ampv, float* __restrict__ attv,
    float* __restrict__ invd, float* __restrict__ hnb) {
  __shared__ int sh[1024];
  int t = threadIdx.x;
  int base = t * 20;
  int local[20];
  int s = 0;
#pragma unroll
  for (int i = 0; i < 20; i++) {
    int idx = base + i;
    int v = (idx < N_) ? deg[idx] : 0;
    local[i] = s; s += v;
  }
  sh[t] = s;
  __syncthreads();
  for (int off = 1; off < 1024; off <<= 1) {
    int v = (t >= off) ? sh[t - off] : 0;
    __syncthreads();
    sh[t] += v;
    __syncthreads();
  }
  int excl = sh[t] - s;
#pragma unroll
  for (int i = 0; i < 20; i++) {
    int idx = base + i;
    if (idx < N_) offs[idx] = excl + local[i];
  }
  if (t == 0) offs[N_] = sh[1023];
  for (int idx = t; idx < N_; idx += 1024) {
    float d = (float)deg[idx];
    float logd = logf(d + 1.f);
    ampv[idx] = logd / AVG_D_LOG;
    attv[idx] = AVG_D_LOG / fmaxf(logd, 1e-5f);
    invd[idx] = 1.f / fmaxf(d, 1.f);
    hnb[idx] = d > 0.f ? 1.f : 0.f;
  }
}

__global__ __launch_bounds__(256) void k_scatter(const int* __restrict__ src, const int* __restrict__ dst,
    const int* __restrict__ offs, int* __restrict__ cursor, int* __restrict__ csr) {
  int e = blockIdx.x * 256 + threadIdx.x;
  if (e < E_) {
    int d = dst[e];
    int pos = offs[d] + atomicAdd(&cursor[d], 1);
    csr[pos] = src[e];
  }
}

// ---------------- embedding ----------------

__global__ __launch_bounds__(256) void k_embed(const float* __restrict__ h, const float* __restrict__ embW,
    const float* __restrict__ embB, float* __restrict__ x) {
  int n = blockIdx.x * 4 + (threadIdx.x >> 6);
  int c = threadIdx.x & 63;
  float acc = embB[c];
#pragma unroll
  for (int k = 0; k < IN_; k++) acc += h[n * IN_ + k] * embW[k * H_ + c];
  x[n * H_ + c] = acc;
}

// ---------------- pretrans: a = x@W_top, b = x@W_bot + bias ----------------
// 16 nodes/block, 256 threads (thread = 1 node x 4 channels), grid 1250
// -> ~20 waves/CU. x staged in LDS; W streams from L2.

__global__ __launch_bounds__(256, 4) void k_pretrans(const float* __restrict__ x, const float* __restrict__ W,
    const float* __restrict__ Bv, float* __restrict__ a, float* __restrict__ b) {
  __shared__ float xs[16 * 68];
  int tid = threadIdx.x;
  int n0 = blockIdx.x * 16;
  {
    int node = tid >> 4, col = (tid & 15) * 4;
    *(float4*)(xs + node * 68 + col) = *(const float4*)(x + (size_t)(n0 + node) * 64 + col);
  }
  __syncthreads();
  int cq = tid & 15, nl = tid >> 4;
  int c4 = cq * 4;
  const float* xp = xs + nl * 68;
  F4 accA, accB;
  accA.v = make_float4(0.f, 0.f, 0.f, 0.f);
  accB.v = *(const float4*)(Bv + c4);
#pragma unroll 2
  for (int k = 0; k < 64; k += 4) {
    F4 xv; xv.v = *(const float4*)(xp + k);
#pragma unroll
    for (int kk = 0; kk < 4; kk++) {
      F4 wa, wb;
      wa.v = *(const float4*)(W + (k + kk) * 64 + c4);
      wb.v = *(const float4*)(W + (64 + k + kk) * 64 + c4);
      float m = xv.f[kk];
#pragma unroll
      for (int j = 0; j < 4; j++) {
        accA.f[j] += m * wa.f[j];
        accB.f[j] += m * wb.f[j];
      }
    }
  }
  int n = n0 + nl;
  *(float4*)(a + (size_t)n * 64 + c4) = accA.v;
  *(float4*)(b + (size_t)n * 64 + c4) = accB.v;
}

// ---------------- aggregation: wave per node, 4 edges in flight ----------------

__global__ __launch_bounds__(256) void k_agg(const float* __restrict__ a, const float* __restrict__ b,
    const int* __restrict__ offs, const int* __restrict__ csr,
    const float* __restrict__ invd, const float* __restrict__ hnb, float* __restrict__ agg) {
  int lane = threadIdx.x & 63;
  int n = (blockIdx.x * 256 + threadIdx.x) >> 6;
  int q = lane & 15;    // channel quad: channels 4q..4q+3
  int eg = lane >> 4;   // edge group 0..3
  int o0 = offs[n];
  int deg = offs[n + 1] - o0;
  F4 bv; bv.v = *(const float4*)(b + n * 64 + q * 4);
  F4 sum, sq, mx, mn;
#pragma unroll
  for (int i = 0; i < 4; i++) {
    sum.f[i] = 0.f; sq.f[i] = 0.f;
    mx.f[i] = -__builtin_inff(); mn.f[i] = __builtin_inff();
  }
  for (int j = eg; j < deg; j += 4) {
    int s = csr[o0 + j];
    F4 av; av.v = *(const float4*)(a + s * 64 + q * 4);
#pragma unroll
    for (int i = 0; i < 4; i++) {
      float m = av.f[i] + bv.f[i];
      sum.f[i] += m;
      sq.f[i] += m * m;
      mx.f[i] = fmaxf(mx.f[i], m);
      mn.f[i] = fminf(mn.f[i], m);
    }
  }
#pragma unroll
  for (int off = 16; off < 64; off <<= 1) {
#pragma unroll
    for (int i = 0; i < 4; i++) {
      sum.f[i] += __shfl_xor(sum.f[i], off);
      sq.f[i]  += __shfl_xor(sq.f[i], off);
      mx.f[i]  = fmaxf(mx.f[i], __shfl_xor(mx.f[i], off));
      mn.f[i]  = fminf(mn.f[i], __shfl_xor(mn.f[i], off));
    }
  }
  if (eg == 0) {
    float inv = invd[n], hn = hnb[n];
    F4 mean, stdv, mxo, mno;
#pragma unroll
    for (int i = 0; i < 4; i++) {
      mean.f[i] = sum.f[i] * inv;
      float var = sq.f[i] * inv - mean.f[i] * mean.f[i];
      stdv.f[i] = sqrtf(fmaxf(var, 0.f) + 1e-5f);
      mxo.f[i] = (hn > 0.5f) ? mx.f[i] : 0.f;
      mno.f[i] = (hn > 0.5f) ? mn.f[i] : 0.f;
    }
    *(float4*)(agg + n * 256 + q * 4) = mean.v;
    *(float4*)(agg + n * 256 + 64 + q * 4) = mxo.v;
    *(float4*)(agg + n * 256 + 128 + q * 4) = mno.v;
    *(float4*)(agg + n * 256 + 192 + q * 4) = stdv.v;
  }
}

// ---------------- posttrans + mix + graphnorm + residual (fused) ----------------
// 16 nodes/block, 256 threads (thread = 1 node x 4 channels), grid 1250
// -> ~20 waves/CU (R4's 1-wave-block latency bind fixed). agg+x staged in
// LDS once; W streams from L2; 3 accumulator sets (identity/amp/att).

__global__ __launch_bounds__(256, 4) void k_post(
    const float* __restrict__ agg, const float* __restrict__ W, const float* __restrict__ Bv,
    const float* __restrict__ mixW, const float* __restrict__ mixB,
    const float* __restrict__ ampv, const float* __restrict__ attv,
    const float* __restrict__ snorm, float* __restrict__ x) {
  __shared__ float aggs[16 * 260];  // padded: rows shift 4 banks
  __shared__ float xs[16 * 68];
  __shared__ float ys[16 * 68];
  int tid = threadIdx.x;
  int n0 = blockIdx.x * 16;
#pragma unroll
  for (int s = 0; s < 4; s++) {
    int fi = tid + s * 256;
    int node = fi >> 6, col = (fi & 63) * 4;
    *(float4*)(aggs + node * 260 + col) = *(const float4*)(agg + (size_t)(n0 + node) * 256 + col);
  }
  {
    int node = tid >> 4, col = (tid & 15) * 4;
    *(float4*)(xs + node * 68 + col) = *(const float4*)(x + (size_t)(n0 + node) * 64 + col);
  }
  __syncthreads();
  int cq = tid & 15, nl = tid >> 4;
  int c4 = cq * 4;
  int n = n0 + nl;
  F4 uI, uA, uT;
  uI.v = make_float4(0.f, 0.f, 0.f, 0.f);
  uA.v = make_float4(0.f, 0.f, 0.f, 0.f);
  uT.v = make_float4(0.f, 0.f, 0.f, 0.f);
  const float* ap = aggs + nl * 260;
  // main GEMM over 256 agg columns, 3 W segments at once
#pragma unroll 2
  for (int k = 0; k < 256; k += 4) {
    F4 av; av.v = *(const float4*)(ap + k);
#pragma unroll
    for (int kk = 0; kk < 4; kk++) {
      F4 w0, w1, w2;
      w0.v = *(const float4*)(W + (k + kk) * 64 + c4);
      w1.v = *(const float4*)(W + (256 + k + kk) * 64 + c4);
      w2.v = *(const float4*)(W + (512 + k + kk) * 64 + c4);
      float m = av.f[kk];
#pragma unroll
      for (int j = 0; j < 4; j++) {
        uI.f[j] += m * w0.f[j];
        uA.f[j] += m * w1.f[j];
        uT.f[j] += m * w2.f[j];
      }
    }
  }
  // x part: rows 768..831 into identity accumulator
  const float* xp = xs + nl * 68;
#pragma unroll 2
  for (int k = 0; k < 64; k += 4) {
    F4 xv; xv.v = *(const float4*)(xp + k);
#pragma unroll
    for (int kk = 0; kk < 4; kk++) {
      F4 w; w.v = *(const float4*)(W + (768 + k + kk) * 64 + c4);
      float m = xv.f[kk];
#pragma unroll
      for (int j = 0; j < 4; j++) uI.f[j] += m * w.f[j];
    }
  }
  // combine scalers + bias -> stage y into LDS for mix
  {
    float amp = ampv[n], att = attv[n];
    F4 bias; bias.v = *(const float4*)(Bv + c4);
    F4 y;
#pragma unroll
    for (int j = 0; j < 4; j++)
      y.f[j] = uI.f[j] + bias.f[j] + amp * uA.f[j] + att * uT.f[j];
    *(float4*)(ys + nl * 68 + c4) = y.v;
  }
  __syncthreads();
  // mix: t = leaky_relu(y @ mixW + mixB); x = x_in + t * snorm
  F4 acc; acc.v = *(const float4*)(mixB + c4);
  const float* yp = ys + nl * 68;
#pragma unroll 2
  for (int k = 0; k < 64; k += 4) {
    F4 yv; yv.v = *(const float4*)(yp + k);
#pragma unroll
    for (int kk = 0; kk < 4; kk++) {
      F4 w; w.v = *(const float4*)(mixW + (k + kk) * 64 + c4);
      float m = yv.f[kk];
#pragma unroll
      for (int j = 0; j < 4; j++) acc.f[j] += m * w.f[j];
    }
  }
  {
    float sn = snorm[n];
    F4 xv; xv.v = *(const float4*)(xp + c4);
    F4 outv;
#pragma unroll
    for (int j = 0; j < 4; j++) {
      float t2 = acc.f[j];
      t2 = t2 > 0.f ? t2 : 0.01f * t2;
      outv.f[j] = xv.f[j] + t2 * sn;
    }
    *(float4*)(x + (size_t)n * 64 + c4) = outv.v;
  }
}

// ---------------- fused readout: segmented mean (gid sorted) + MLP ----------------

__device__ inline int lower_bound_gid(const int* __restrict__ gid, int val) {
  int lo = 0, hi = N_;
  while (lo < hi) {
    int mid = (lo + hi) >> 1;
    if (gid[mid] < val) lo = mid + 1; else hi = mid;
  }
  return lo;
}

__global__ __launch_bounds__(256) void k_readout_fused(
    const float* __restrict__ x, const int* __restrict__ gid,
    const float* __restrict__ r1W, const float* __restrict__ r1B,
    const float* __restrict__ r2W, const float* __restrict__ r2B,
    const float* __restrict__ r3W, const float* __restrict__ r3B,
    float* __restrict__ out) {
  __shared__ float part[4 * 64];
  __shared__ float hg[64];
  __shared__ float t1[32];
  __shared__ float t2[16];
  int g = blockIdx.x, tid = threadIdx.x;
  int lo = lower_bound_gid(gid, g);
  int hi = lower_bound_gid(gid, g + 1);
  int c = tid & 63, w = tid >> 6;
  float s = 0.f;
  for (int n = lo + w; n < hi; n += 4) s += x[(size_t)n * 64 + c];
  part[w * 64 + c] = s;
  __syncthreads();
  if (w == 0) {
    float tot = part[c] + part[64 + c] + part[128 + c] + part[192 + c];
    float cnt = (float)(hi - lo);
    if (cnt < 1.f) cnt = 1.f;
    hg[c] = tot / cnt;
  }
  __syncthreads();
  if (tid < 32) {
    float acc = r1B[tid];
#pragma unroll 8
    for (int k = 0; k < 64; k++) acc += hg[k] * r1W[k * 32 + tid];
    t1[tid] = fmaxf(acc, 0.f);
  }
  __syncthreads();
  if (tid < 16) {
    float acc = r2B[tid];
#pragma unroll 8
    for (int k = 0; k < 32; k++) acc += t1[k] * r2W[k * 16 + tid];
    t2[tid] = fmaxf(acc, 0.f);
  }
  __syncthreads();
  if (tid < 10) {
    float acc = r3B[tid];
#pragma unroll
    for (int k = 0; k < 16; k++) acc += t2[k] * r3W[k * 10 + tid];
    out[g * 10 + tid] = acc;
  }
}

// ---------------- launch ----------------

extern "C" void kernel_launch(void* const* d_in, const int* in_sizes, int n_in,
                              void* d_out, int out_size, void* d_ws, size_t ws_size,
                              hipStream_t stream) {
  const float* h     = (const float*)d_in[0];
  const float* snorm = (const float*)d_in[1];
  const float* embW  = (const float*)d_in[2];
  const float* embB  = (const float*)d_in[3];
  const float* preW  = (const float*)d_in[4];
  const float* preB  = (const float*)d_in[5];
  const float* postW = (const float*)d_in[6];
  const float* postB = (const float*)d_in[7];
  const float* mixW  = (const float*)d_in[8];
  const float* mixB  = (const float*)d_in[9];
  const float* r1W   = (const float*)d_in[10];
  const float* r1B   = (const float*)d_in[11];
  const float* r2W   = (const float*)d_in[12];
  const float* r2B   = (const float*)d_in[13];
  const float* r3W   = (const float*)d_in[14];
  const float* r3B   = (const float*)d_in[15];
  const int* src     = (const int*)d_in[16];
  const int* dst     = (const int*)d_in[17];
  const int* gid     = (const int*)d_in[18];
  float* out = (float*)d_out;

  char* w = (char*)d_ws;
  float* x    = (float*)w; w += (size_t)N_ * 64 * 4;
  float* av   = (float*)w; w += (size_t)N_ * 64 * 4;
  float* bv   = (float*)w; w += (size_t)N_ * 64 * 4;
  float* agg  = (float*)w; w += (size_t)N_ * 256 * 4;
  float* ampv = (float*)w; w += (size_t)N_ * 4;
  float* attv = (float*)w; w += (size_t)N_ * 4;
  float* invd = (float*)w; w += (size_t)N_ * 4;
  float* hnb  = (float*)w; w += (size_t)N_ * 4;
  int* csr    = (int*)w;   w += (size_t)E_ * 4;
  int* offs   = (int*)w;   w += (size_t)(N_ + 64) * 4;
  int* zbase  = (int*)w;
  int* deg    = (int*)w;   w += (size_t)N_ * 4;
  int* cursor = (int*)w;   w += (size_t)N_ * 4;
  int zcount = N_ + N_;

  k_zero<<<(zcount + 255) / 256, 256, 0, stream>>>(zbase, zcount);
  k_hist<<<E_ / 256, 256, 0, stream>>>(dst, deg);
  k_scan<<<1, 1024, 0, stream>>>(deg, offs, ampv, attv, invd, hnb);
  k_scatter<<<E_ / 256, 256, 0, stream>>>(src, dst, offs, cursor, csr);
  k_embed<<<N_ / 4, 256, 0, stream>>>(h, embW, embB, x);
  for (int l = 0; l < L_; l++) {
    k_pretrans<<<N_ / 16, 256, 0, stream>>>(x, preW + l * 2 * H_ * H_, preB + l * H_, av, bv);
    k_agg<<<N_ / 4, 256, 0, stream>>>(av, bv, offs, csr, invd, hnb, agg);
    k_post<<<N_ / 16, 256, 0, stream>>>(agg, postW + l * 13 * H_ * H_, postB + l * H_,
                                        mixW + l * H_ * H_, mixB + l * H_, ampv, attv, snorm, x);
  }
  k_readout_fused<<<G_, 256, 0, stream>>>(x, gid, r1W, r1B, r2W, r2B, r3W, r3B, out);
}

// Round 6
// 641.429 us; speedup vs baseline: 1.4185x; 1.3331x over previous
//
#include <hip/hip_runtime.h>
#include <math.h>

#define N_ 20000
#define E_ 320000
#define G_ 128
#define IN_ 16
#define H_ 64
#define L_ 4
#define C_ 10
#define AVG_D_LOG 2.8332133440562162f

union F4 { float4 v; float f[4]; };

// ---------------- preprocessing ----------------

__global__ __launch_bounds__(256) void k_zero(int* __restrict__ p, int n) {
  int i = blockIdx.x * 256 + threadIdx.x;
  if (i < n) p[i] = 0;
}

__global__ __launch_bounds__(256) void k_hist(const int* __restrict__ dst, int* __restrict__ deg) {
  int e = blockIdx.x * 256 + threadIdx.x;
  if (e < E_) atomicAdd(&deg[dst[e]], 1);
}

__global__ __launch_bounds__(1024) void k_scan(const int* __restrict__ deg, int* __restrict__ offs,
    float* __restrict__ ampv, float* __restrict__ attv,
    float* __restrict__ invd, float* __restrict__ hnb) {
  __shared__ int sh[1024];
  int t = threadIdx.x;
  int base = t * 20;
  int local[20];
  int s = 0;
#pragma unroll
  for (int i = 0; i < 20; i++) {
    int idx = base + i;
    int v = (idx < N_) ? deg[idx] : 0;
    local[i] = s; s += v;
  }
  sh[t] = s;
  __syncthreads();
  for (int off = 1; off < 1024; off <<= 1) {
    int v = (t >= off) ? sh[t - off] : 0;
    __syncthreads();
    sh[t] += v;
    __syncthreads();
  }
  int excl = sh[t] - s;
#pragma unroll
  for (int i = 0; i < 20; i++) {
    int idx = base + i;
    if (idx < N_) offs[idx] = excl + local[i];
  }
  if (t == 0) offs[N_] = sh[1023];
  for (int idx = t; idx < N_; idx += 1024) {
    float d = (float)deg[idx];
    float logd = logf(d + 1.f);
    ampv[idx] = logd / AVG_D_LOG;
    attv[idx] = AVG_D_LOG / fmaxf(logd, 1e-5f);
    invd[idx] = 1.f / fmaxf(d, 1.f);
    hnb[idx] = d > 0.f ? 1.f : 0.f;
  }
}

__global__ __launch_bounds__(256) void k_scatter(const int* __restrict__ src, const int* __restrict__ dst,
    const int* __restrict__ offs, int* __restrict__ cursor, int* __restrict__ csr) {
  int e = blockIdx.x * 256 + threadIdx.x;
  if (e < E_) {
    int d = dst[e];
    int pos = offs[d] + atomicAdd(&cursor[d], 1);
    csr[pos] = src[e];
  }
}

// ---------------- embedding ----------------

__global__ __launch_bounds__(256) void k_embed(const float* __restrict__ h, const float* __restrict__ embW,
    const float* __restrict__ embB, float* __restrict__ x) {
  int n = blockIdx.x * 4 + (threadIdx.x >> 6);
  int c = threadIdx.x & 63;
  float acc = embB[c];
#pragma unroll
  for (int k = 0; k < IN_; k++) acc += h[n * IN_ + k] * embW[k * H_ + c];
  x[n * H_ + c] = acc;
}

// ---------------- pretrans (SGPR-broadcast): lane = node, wave = 32 out-ch ----------------
// out = x @ [Wtop | Wbot] (+bias on b half). W values wave-uniform -> scalar loads.

__global__ __launch_bounds__(256) void k_pretrans(const float* __restrict__ x, const float* __restrict__ W,
    const float* __restrict__ Bv, float* __restrict__ a, float* __restrict__ b) {
  __shared__ float otile[64 * 132];   // 64 nodes x 128 out-ch (padded)
  __shared__ float xs[64 * 68];
  int tid = threadIdx.x;
  int n0 = blockIdx.x * 64;
  int lane = tid & 63;
  int wv = __builtin_amdgcn_readfirstlane(tid >> 6);
  int ch0 = wv * 32;                  // out-ch 0..127 across 4 waves
  // stage x tile (coalesced)
#pragma unroll
  for (int i = 0; i < 4; i++) {
    int fi = tid + i * 256;
    int node = fi >> 4, c4 = (fi & 15) * 4;
    int ng = n0 + node; if (ng > N_ - 1) ng = N_ - 1;
    *(float4*)(xs + node * 68 + c4) = *(const float4*)(x + (size_t)ng * 64 + c4);
  }
  __syncthreads();
  float acc[32];
#pragma unroll
  for (int j = 0; j < 32; j++) acc[j] = 0.f;
  // W row base for this wave's channels: ch<64 -> Wtop rows 0..63; else Wbot rows 64..127
  const float* Wb = W + (ch0 < 64 ? 0 : 64 * 64) ;
  int cb = (ch0 < 64) ? ch0 : (ch0 - 64);
  const float* xp = xs + lane * 68;
#pragma unroll 2
  for (int k = 0; k < 64; k += 4) {
    F4 xv; xv.v = *(const float4*)(xp + k);
#pragma unroll
    for (int kk = 0; kk < 4; kk++) {
      const float* wrow = Wb + (k + kk) * 64 + cb;
      float m = xv.f[kk];
#pragma unroll
      for (int j = 0; j < 32; j++) acc[j] += m * wrow[j];
    }
  }
  if (ch0 >= 64) {
#pragma unroll
    for (int j = 0; j < 32; j++) acc[j] += Bv[cb + j];
  }
  // per-lane row write into otile, then coalesced store
#pragma unroll
  for (int j = 0; j < 32; j += 4) {
    F4 t2; t2.f[0] = acc[j]; t2.f[1] = acc[j+1]; t2.f[2] = acc[j+2]; t2.f[3] = acc[j+3];
    *(float4*)(otile + lane * 132 + ch0 + j) = t2.v;
  }
  __syncthreads();
#pragma unroll
  for (int i = 0; i < 8; i++) {
    int fi = tid + i * 256;
    int node = fi >> 5, c4 = (fi & 31) * 4;
    int n = n0 + node;
    if (n < N_) {
      F4 v; v.v = *(const float4*)(otile + node * 132 + c4);
      if (c4 < 64) *(float4*)(a + (size_t)n * 64 + c4) = v.v;
      else         *(float4*)(b + (size_t)n * 64 + (c4 - 64)) = v.v;
    }
  }
}

// ---------------- aggregation: wave per node, 4 edges in flight ----------------

__global__ __launch_bounds__(256) void k_agg(const float* __restrict__ a, const float* __restrict__ b,
    const int* __restrict__ offs, const int* __restrict__ csr,
    const float* __restrict__ invd, const float* __restrict__ hnb, float* __restrict__ agg) {
  int lane = threadIdx.x & 63;
  int n = (blockIdx.x * 256 + threadIdx.x) >> 6;
  int q = lane & 15;
  int eg = lane >> 4;
  int o0 = offs[n];
  int deg = offs[n + 1] - o0;
  F4 bv; bv.v = *(const float4*)(b + n * 64 + q * 4);
  F4 sum, sq, mx, mn;
#pragma unroll
  for (int i = 0; i < 4; i++) {
    sum.f[i] = 0.f; sq.f[i] = 0.f;
    mx.f[i] = -__builtin_inff(); mn.f[i] = __builtin_inff();
  }
  for (int j = eg; j < deg; j += 4) {
    int s = csr[o0 + j];
    F4 av; av.v = *(const float4*)(a + s * 64 + q * 4);
#pragma unroll
    for (int i = 0; i < 4; i++) {
      float m = av.f[i] + bv.f[i];
      sum.f[i] += m;
      sq.f[i] += m * m;
      mx.f[i] = fmaxf(mx.f[i], m);
      mn.f[i] = fminf(mn.f[i], m);
    }
  }
#pragma unroll
  for (int off = 16; off < 64; off <<= 1) {
#pragma unroll
    for (int i = 0; i < 4; i++) {
      sum.f[i] += __shfl_xor(sum.f[i], off);
      sq.f[i]  += __shfl_xor(sq.f[i], off);
      mx.f[i]  = fmaxf(mx.f[i], __shfl_xor(mx.f[i], off));
      mn.f[i]  = fminf(mn.f[i], __shfl_xor(mn.f[i], off));
    }
  }
  if (eg == 0) {
    float inv = invd[n], hn = hnb[n];
    F4 mean, stdv, mxo, mno;
#pragma unroll
    for (int i = 0; i < 4; i++) {
      mean.f[i] = sum.f[i] * inv;
      float var = sq.f[i] * inv - mean.f[i] * mean.f[i];
      stdv.f[i] = sqrtf(fmaxf(var, 0.f) + 1e-5f);
      mxo.f[i] = (hn > 0.5f) ? mx.f[i] : 0.f;
      mno.f[i] = (hn > 0.5f) ? mn.f[i] : 0.f;
    }
    *(float4*)(agg + n * 256 + q * 4) = mean.v;
    *(float4*)(agg + n * 256 + 64 + q * 4) = mxo.v;
    *(float4*)(agg + n * 256 + 128 + q * 4) = mno.v;
    *(float4*)(agg + n * 256 + 192 + q * 4) = stdv.v;
  }
}

// ---------------- posttrans + mix + graphnorm + residual (SGPR-broadcast) ----------------
// lane = node (64 nodes/block), wave = 16 out-ch. W/mixW values wave-uniform ->
// scalar loads (off the VMEM pipe). agg streamed through LDS in two 128-col
// chunks; y transposed via LDS (aliases aggs) for the mix GEMM; coalesced store.

__global__ __launch_bounds__(256) void k_post(
    const float* __restrict__ agg, const float* __restrict__ W, const float* __restrict__ Bv,
    const float* __restrict__ mixW, const float* __restrict__ mixB,
    const float* __restrict__ ampv, const float* __restrict__ attv,
    const float* __restrict__ snorm, float* __restrict__ x) {
  __shared__ float aggs[64 * 132];   // chunk buffer; later reused as y tile + out tile
  __shared__ float xs[64 * 68];
  float* ys = aggs;                  // alias (aggs dead before y is written)
  int tid = threadIdx.x;
  int n0 = blockIdx.x * 64;
  int lane = tid & 63;
  int wv = __builtin_amdgcn_readfirstlane(tid >> 6);
  int ch0 = wv * 16;
  int n = n0 + lane;
  int nc = n > N_ - 1 ? N_ - 1 : n;
  // stage x tile
#pragma unroll
  for (int i = 0; i < 4; i++) {
    int fi = tid + i * 256;
    int node = fi >> 4, c4 = (fi & 15) * 4;
    int ng = n0 + node; if (ng > N_ - 1) ng = N_ - 1;
    *(float4*)(xs + node * 68 + c4) = *(const float4*)(x + (size_t)ng * 64 + c4);
  }
  float uI[16], uA[16], uT[16];
#pragma unroll
  for (int j = 0; j < 16; j++) { uI[j] = 0.f; uA[j] = 0.f; uT[j] = 0.f; }
  // two K-chunks of 128 agg columns
#pragma unroll 1
  for (int ck = 0; ck < 2; ck++) {
    __syncthreads();
#pragma unroll
    for (int i = 0; i < 8; i++) {
      int fi = tid + i * 256;
      int node = fi >> 5, c4 = (fi & 31) * 4;
      int ng = n0 + node; if (ng > N_ - 1) ng = N_ - 1;
      *(float4*)(aggs + node * 132 + c4) =
          *(const float4*)(agg + (size_t)ng * 256 + ck * 128 + c4);
    }
    __syncthreads();
    const float* ap = aggs + lane * 132;
#pragma unroll 2
    for (int k = 0; k < 128; k += 4) {
      F4 av; av.v = *(const float4*)(ap + k);
#pragma unroll
      for (int kk = 0; kk < 4; kk++) {
        int row = ck * 128 + k + kk;
        const float* w0 = W + row * 64 + ch0;
        const float* w1 = W + (256 + row) * 64 + ch0;
        const float* w2 = W + (512 + row) * 64 + ch0;
        float m = av.f[kk];
#pragma unroll
        for (int j = 0; j < 16; j++) {
          uI[j] += m * w0[j];
          uA[j] += m * w1[j];
          uT[j] += m * w2[j];
        }
      }
    }
  }
  // x part: rows 768..831 into identity accumulator
  {
    const float* xp = xs + lane * 68;
#pragma unroll 2
    for (int k = 0; k < 64; k += 4) {
      F4 xv; xv.v = *(const float4*)(xp + k);
#pragma unroll
      for (int kk = 0; kk < 4; kk++) {
        const float* w3 = W + (768 + k + kk) * 64 + ch0;
        float m = xv.f[kk];
#pragma unroll
        for (int j = 0; j < 16; j++) uI[j] += m * w3[j];
      }
    }
  }
  // combine scalers + bias -> y (write per-lane row into ys, which aliases aggs)
  float amp = ampv[nc], att = attv[nc];
  __syncthreads();   // all aggs reads complete before overwrite
#pragma unroll
  for (int j = 0; j < 16; j += 4) {
    F4 y;
#pragma unroll
    for (int q = 0; q < 4; q++)
      y.f[q] = uI[j+q] + Bv[ch0 + j + q] + amp * uA[j+q] + att * uT[j+q];
    *(float4*)(ys + lane * 132 + ch0 + j) = y.v;
  }
  __syncthreads();
  // mix: t = leaky_relu(y @ mixW + mixB); out = x_in + t * snorm
  float acc[16];
#pragma unroll
  for (int j = 0; j < 16; j++) acc[j] = mixB[ch0 + j];
  {
    const float* yp = ys + lane * 132;
#pragma unroll 2
    for (int k = 0; k < 64; k += 4) {
      F4 yv; yv.v = *(const float4*)(yp + k);
#pragma unroll
      for (int kk = 0; kk < 4; kk++) {
        const float* w = mixW + (k + kk) * 64 + ch0;
        float m = yv.f[kk];
#pragma unroll
        for (int j = 0; j < 16; j++) acc[j] += m * w[j];
      }
    }
  }
  float sn = snorm[nc];
  __syncthreads();   // all ys reads complete before overwrite with outputs
#pragma unroll
  for (int j = 0; j < 16; j += 4) {
    F4 xin; xin.v = *(const float4*)(xs + lane * 68 + ch0 + j);
    F4 outv;
#pragma unroll
    for (int q = 0; q < 4; q++) {
      float t2 = acc[j+q];
      t2 = t2 > 0.f ? t2 : 0.01f * t2;
      outv.f[q] = xin.f[q] + t2 * sn;
    }
    *(float4*)(ys + lane * 132 + ch0 + j) = outv.v;
  }
  __syncthreads();
  // coalesced store
#pragma unroll
  for (int i = 0; i < 4; i++) {
    int fi = tid + i * 256;
    int node = fi >> 4, c4 = (fi & 15) * 4;
    int ng = n0 + node;
    if (ng < N_) {
      F4 v; v.v = *(const float4*)(ys + node * 132 + c4);
      *(float4*)(x + (size_t)ng * 64 + c4) = v.v;
    }
  }
}

// ---------------- fused readout: segmented mean (gid sorted) + MLP ----------------

__device__ inline int lower_bound_gid(const int* __restrict__ gid, int val) {
  int lo = 0, hi = N_;
  while (lo < hi) {
    int mid = (lo + hi) >> 1;
    if (gid[mid] < val) lo = mid + 1; else hi = mid;
  }
  return lo;
}

__global__ __launch_bounds__(256) void k_readout_fused(
    const float* __restrict__ x, const int* __restrict__ gid,
    const float* __restrict__ r1W, const float* __restrict__ r1B,
    const float* __restrict__ r2W, const float* __restrict__ r2B,
    const float* __restrict__ r3W, const float* __restrict__ r3B,
    float* __restrict__ out) {
  __shared__ float part[4 * 64];
  __shared__ float hg[64];
  __shared__ float t1[32];
  __shared__ float t2[16];
  int g = blockIdx.x, tid = threadIdx.x;
  int lo = lower_bound_gid(gid, g);
  int hi = lower_bound_gid(gid, g + 1);
  int c = tid & 63, w = tid >> 6;
  float s = 0.f;
  for (int n = lo + w; n < hi; n += 4) s += x[(size_t)n * 64 + c];
  part[w * 64 + c] = s;
  __syncthreads();
  if (w == 0) {
    float tot = part[c] + part[64 + c] + part[128 + c] + part[192 + c];
    float cnt = (float)(hi - lo);
    if (cnt < 1.f) cnt = 1.f;
    hg[c] = tot / cnt;
  }
  __syncthreads();
  if (tid < 32) {
    float acc = r1B[tid];
#pragma unroll 8
    for (int k = 0; k < 64; k++) acc += hg[k] * r1W[k * 32 + tid];
    t1[tid] = fmaxf(acc, 0.f);
  }
  __syncthreads();
  if (tid < 16) {
    float acc = r2B[tid];
#pragma unroll 8
    for (int k = 0; k < 32; k++) acc += t1[k] * r2W[k * 16 + tid];
    t2[tid] = fmaxf(acc, 0.f);
  }
  __syncthreads();
  if (tid < 10) {
    float acc = r3B[tid];
#pragma unroll
    for (int k = 0; k < 16; k++) acc += t2[k] * r3W[k * 10 + tid];
    out[g * 10 + tid] = acc;
  }
}

// ---------------- launch ----------------

extern "C" void kernel_launch(void* const* d_in, const int* in_sizes, int n_in,
                              void* d_out, int out_size, void* d_ws, size_t ws_size,
                              hipStream_t stream) {
  const float* h     = (const float*)d_in[0];
  const float* snorm = (const float*)d_in[1];
  const float* embW  = (const float*)d_in[2];
  const float* embB  = (const float*)d_in[3];
  const float* preW  = (const float*)d_in[4];
  const float* preB  = (const float*)d_in[5];
  const float* postW = (const float*)d_in[6];
  const float* postB = (const float*)d_in[7];
  const float* mixW  = (const float*)d_in[8];
  const float* mixB  = (const float*)d_in[9];
  const float* r1W   = (const float*)d_in[10];
  const float* r1B   = (const float*)d_in[11];
  const float* r2W   = (const float*)d_in[12];
  const float* r2B   = (const float*)d_in[13];
  const float* r3W   = (const float*)d_in[14];
  const float* r3B   = (const float*)d_in[15];
  const int* src     = (const int*)d_in[16];
  const int* dst     = (const int*)d_in[17];
  const int* gid     = (const int*)d_in[18];
  float* out = (float*)d_out;

  char* w = (char*)d_ws;
  float* x    = (float*)w; w += (size_t)N_ * 64 * 4;
  float* av   = (float*)w; w += (size_t)N_ * 64 * 4;
  float* bv   = (float*)w; w += (size_t)N_ * 64 * 4;
  float* agg  = (float*)w; w += (size_t)N_ * 256 * 4;
  float* ampv = (float*)w; w += (size_t)N_ * 4;
  float* attv = (float*)w; w += (size_t)N_ * 4;
  float* invd = (float*)w; w += (size_t)N_ * 4;
  float* hnb  = (float*)w; w += (size_t)N_ * 4;
  int* csr    = (int*)w;   w += (size_t)E_ * 4;
  int* offs   = (int*)w;   w += (size_t)(N_ + 64) * 4;
  int* zbase  = (int*)w;
  int* deg    = (int*)w;   w += (size_t)N_ * 4;
  int* cursor = (int*)w;   w += (size_t)N_ * 4;
  int zcount = N_ + N_;

  k_zero<<<(zcount + 255) / 256, 256, 0, stream>>>(zbase, zcount);
  k_hist<<<E_ / 256, 256, 0, stream>>>(dst, deg);
  k_scan<<<1, 1024, 0, stream>>>(deg, offs, ampv, attv, invd, hnb);
  k_scatter<<<E_ / 256, 256, 0, stream>>>(src, dst, offs, cursor, csr);
  k_embed<<<N_ / 4, 256, 0, stream>>>(h, embW, embB, x);
  int gb = (N_ + 63) / 64;
  for (int l = 0; l < L_; l++) {
    k_pretrans<<<gb, 256, 0, stream>>>(x, preW + l * 2 * H_ * H_, preB + l * H_, av, bv);
    k_agg<<<N_ / 4, 256, 0, stream>>>(av, bv, offs, csr, invd, hnb, agg);
    k_post<<<gb, 256, 0, stream>>>(agg, postW + l * 13 * H_ * H_, postB + l * H_,
                                   mixW + l * H_ * H_, mixB + l * H_, ampv, attv, snorm, x);
  }
  k_readout_fused<<<G_, 256, 0, stream>>>(x, gid, r1W, r1B, r2W, r2B, r3W, r3B, out);
}